// Round 16
// baseline (109.066 us; speedup 1.0000x reference)
//
#include <hip/hip_runtime.h>
#include <hip/hip_bf16.h>

// MACE-like GNN on MI355X — MFMA both GEMMs + cross-receiver software pipeline.
// B=32, N=128, F=64, N_RBF=8, H_R=64, L=2.
// Round 16: persistent block over 4 receivers; double-buffered phi/unit/hid;
// per-receiver intervals: {A1(i+1) || B+C(i)} bar {A2(i+1) || tail(i)} bar.

#define NN 128
#define BB 32
#define FF 64

using f32x4  = __attribute__((ext_vector_type(4))) float;
using short8 = __attribute__((ext_vector_type(8))) short;
using half4  = __attribute__((ext_vector_type(4))) _Float16;

__device__ __forceinline__ unsigned short f2bf(float x) {
    unsigned int u = __float_as_uint(x);
    u += 0x7fff + ((u >> 16) & 1);          // RNE
    return (unsigned short)(u >> 16);
}
__device__ __forceinline__ unsigned int f2bf_fast32(float x) {
    return (__float_as_uint(x) + 0x8000u) >> 16;
}

// -------------------- setup: bake weights + init node scalars --------------
__global__ __launch_bounds__(256) void setup_kernel(
    const float* __restrict__ w2,     // [2][64][192]
    const float* __restrict__ ws,     // [2][64][64]
    const float* __restrict__ wv,     // [2][64][64]
    const float* __restrict__ rbf_w1, // [2][8][64]
    const float* __restrict__ rbf_b1, // [2][64]
    const int* __restrict__ species, const float* __restrict__ glob,
    const float* __restrict__ embed, const float* __restrict__ glob_w,
    short* __restrict__ w2frag,       // [2][4][3][2][64][8] = 24576 shorts
    float* __restrict__ wT4,          // [2][2][16][64][4]   = 16384 floats
    _Float16* __restrict__ w1A,       // [2][4][64][4]       = 2048 halfs
    float* __restrict__ s)            // [B*N][64]
{
    const int blk = blockIdx.x;
    if (blk < 192) {
        const int tid = blk * 256 + threadIdx.x;
        const int NFRAG = 24576;
        if (tid < NFRAG) {
            const int e  = tid & 7;
            const int l  = (tid >> 3) & 63;
            const int ks = (tid >> 9) & 1;
            const int q  = tid >> 10;          // layer*12 + wave*3 + nt
            const int nt = q % 3;
            const int wv_ = (q / 3) & 3;
            const int layer = q / 12;
            const int col = nt * 64 + wv_ * 16 + (l & 15);
            const int hb  = ks * 32 + (l >> 4) * 8 + e;
            const float val = w2[layer * 64 * 192 + hb * 192 + col] * (1.0f / 127.0f);
            w2frag[tid] = (short)f2bf(val);
        }
        const int tid2 = tid - NFRAG;
        if (tid2 >= 0 && tid2 < 16384) {
            const int c   = tid2 & 3;
            const int g   = (tid2 >> 2) & 63;
            const int ff4 = (tid2 >> 8) & 15;
            const int m   = (tid2 >> 12) & 1;
            const int layer = tid2 >> 13;
            const float* src = (m == 0 ? ws : wv) + layer * 4096;
            wT4[tid2] = src[(ff4 * 4 + c) * 64 + g];
        }
        const int tid3 = tid - NFRAG - 16384;
        if (tid3 >= 0 && tid3 < 2048) {
            // A-frag 16x16x16: lane l holds A[row=l&15][k=(l>>4)*4+e]
            const int e  = tid3 & 3;
            const int l  = (tid3 >> 2) & 63;
            const int wv_ = (tid3 >> 8) & 3;
            const int layer = tid3 >> 10;
            const int k = (l >> 4) * 4 + e;
            const int h = wv_ * 16 + (l & 15);
            float val = 0.0f;
            if (k < 8)       val = rbf_w1[layer * 512 + k * 64 + h];
            else if (k == 8) val = rbf_b1[layer * 64 + h];
            w1A[tid3] = (_Float16)val;
        }
    } else {
        const int node = (blk - 192) * 4 + (threadIdx.x >> 6);   // b*128 + n
        const int b = node >> 7;
        const int f = threadIdx.x & 63;
        const int sp = species[node];
        float acc = embed[sp * FF + f];
#pragma unroll
        for (int k = 0; k < 16; ++k)
            acc = fmaf(glob[b * 16 + k], glob_w[k * FF + f], acc);
        s[node * FF + f] = acc;
    }
}

// -------------------- fused message+agg+update, 4 receivers/block ----------
// grid 1024 (XCD-swizzled), block 256 = 4 waves; wave w owns f in [16w,16w+16).
template<int LAYER>
__global__ __launch_bounds__(256, 2) void msg_kernel(
    const float* __restrict__ pos,     // [B][N][3]
    const float* __restrict__ s_in,    // [B][N][F]
    const float* __restrict__ v_in,    // [B][N][F][4]  (unused when LAYER==0)
    const half4* __restrict__ w1Abuf,  // [4][64] half4 (layer slice)
    const short* __restrict__ w2frag,  // [4][3][2][64][8] bf16 (layer slice)
    const float* __restrict__ wT4,     // [2][16][64][4] (ws,wv; layer slice)
    const float* __restrict__ wout,    // [64]
    const float* __restrict__ scale,   // [1]
    float* __restrict__ s_out,         // LAYER==0 only
    float* __restrict__ v_out,         // LAYER==0 only, [B][N][F][4]
    float* __restrict__ out)           // LAYER==1 only
{
    __shared__ unsigned short hid_lds[2][NN * 64];       // 32 KB
    __shared__ float4 unit_lds[2][NN];                   // 4 KB
    __shared__ __align__(16) char phi_pool[2][NN * 32];  // 8 KB
    __shared__ float4 agg4[4][16];                       // 1 KB

    // XCD swizzle: 4 consecutive batches per XCD; 4 consecutive receivers/blk.
    const int blk = blockIdx.x;
    const int xcd = blk & 7;
    const int idx = blk >> 3;            // 0..127
    const int b = xcd * 4 + (idx >> 5);
    const int i0 = (idx & 31) * 4;

    const int t = threadIdx.x;
    const int w = t >> 6;          // wave
    const int l = t & 63;          // lane
    const float* pb = pos + b * NN * 3;

    const int f    = w * 16 + (l & 15);
    const int jsub = (l >> 4) * 4;
    const float* sb = s_in + b * NN * FF;
    const float4* vb4 = (LAYER > 0) ? ((const float4*)v_in) + b * NN * FF : nullptr;

    // ---- once-per-block: W2 fragments + W1 a-frag ----
    short8 bfrag[3][2];
    {
        const short8* wf = (const short8*)w2frag;
#pragma unroll
        for (int nt = 0; nt < 3; ++nt) {
            if (LAYER == 0 && nt == 1) continue;
#pragma unroll
            for (int ks = 0; ks < 2; ++ks)
                bfrag[nt][ks] = wf[((w * 3 + nt) * 2 + ks) * 64 + l];
        }
    }
    const half4 w1a = w1Abuf[w * 64 + l];

    // ================= phase bodies (buffers parameterized) =================
    // A1: distance/unit + phi for receiver ie into buffer bf.
    auto A1 = [&](int ie, int bf) {
        const int j = t & 127;
        const int half = t >> 7;
        const float dx = pb[ie * 3 + 0] - pb[j * 3 + 0];
        const float dy = pb[ie * 3 + 1] - pb[j * 3 + 1];
        const float dz = pb[ie * 3 + 2] - pb[j * 3 + 2];
        const float d2 = fmaf(dx, dx, fmaf(dy, dy, fmaf(dz, dz, 1e-12f)));
        const float inv = __builtin_amdgcn_rsqf(d2);
        const float dd = d2 * inv;
        if (half == 0)
            unit_lds[bf][j] = make_float4(dx * inv, dy * inv, dz * inv, 0.0f);
        const _Float16 zf = (_Float16)0.f;
        half4 ph;
#pragma unroll
        for (int rr = 0; rr < 4; ++rr) {
            const float td = dd - (float)(half * 4 + rr) * (5.0f / 7.0f);
            ph[rr] = (_Float16)__expf(td * td * -1.28f);   // 1/(2*0.625^2)
        }
        if (j == ie) ph = (half4){zf, zf, zf, zf};
        char* rowp = phi_pool[bf] + j * 32;
        const int swz = ((j >> 2) & 3) << 3;
        *(half4*)(rowp + ((half * 8) ^ swz)) = ph;
        if (half == 0) {
            half4 bias = {(j == ie) ? zf : (_Float16)1.0f, zf, zf, zf};
            *(half4*)(rowp + (16 ^ swz)) = bias;          // k=8..11
        } else {
            *(half4*)(rowp + (24 ^ swz)) = (half4){zf, zf, zf, zf}; // k=12..15
        }
    };

    // A2: hid(bf) = silu(mfma(W1^T, phi(bf)^T))
    auto A2 = [&](int bf) {
        const int jcol = l & 15;
        const int chunk = (l >> 4) * 8;
        const int hbyte = w * 32 + (l >> 4) * 8;   // h = w*16 + (l>>4)*4 + reg
        const char* phir = phi_pool[bf];
        char* hidr = (char*)hid_lds[bf];
#pragma unroll
        for (int mt = 0; mt < 8; ++mt) {
            const int j = mt * 16 + jcol;
            const half4 bphi = *(const half4*)(
                phir + j * 32 + (chunk ^ (((j >> 2) & 3) << 3)));
            f32x4 pre = __builtin_amdgcn_mfma_f32_16x16x16f16(
                w1a, bphi, (f32x4){0.f, 0.f, 0.f, 0.f}, 0, 0, 0);
            unsigned int pk[2];
#pragma unroll
            for (int p = 0; p < 2; ++p) {
                float sv[2];
#pragma unroll
                for (int q = 0; q < 2; ++q) {
                    const float z = pre[p * 2 + q];
                    const float ex = __expf(-z);
                    sv[q] = z * __builtin_amdgcn_rcpf(1.0f + ex);
                }
                pk[p] = f2bf_fast32(sv[0]) | (f2bf_fast32(sv[1]) << 16);
            }
            const int byte = j * 128 + (hbyte ^ ((j & 7) << 4));
            *(uint2*)(hidr + byte) = make_uint2(pk[0], pk[1]);
        }
    };

    // BC: message MFMAs + consume for buffer bf; writes agg4.
    auto BC = [&](int bf) {
        const char* hidr = (const char*)hid_lds[bf];
        const float4* unitr = unit_lds[bf];
        float accs = 0.f, av0 = 0.f, av1 = 0.f, av2 = 0.f;
        float sP[4]; float4 vP[4];
#pragma unroll
        for (int reg = 0; reg < 4; ++reg) {
            const int j = jsub + reg;
            sP[reg] = sb[j * FF + f];
            if (LAYER > 0) vP[reg] = vb4[j * FF + f];
        }
#pragma unroll
        for (int mt = 0; mt < 8; ++mt) {
            const int jA = mt * 16 + (l & 15);
            const int base = jA * 128;
            const int sw = (jA & 7) << 4;
            const short8 a0 = *(const short8*)(hidr + base + (((l >> 4) * 16 +  0) ^ sw));
            const short8 a1 = *(const short8*)(hidr + base + (((l >> 4) * 16 + 64) ^ sw));

            f32x4 c0 = (f32x4){0.f, 0.f, 0.f, 0.f};
            f32x4 c1 = (f32x4){0.f, 0.f, 0.f, 0.f};
            f32x4 c2 = (f32x4){0.f, 0.f, 0.f, 0.f};
            c0 = __builtin_amdgcn_mfma_f32_16x16x32_bf16(a0, bfrag[0][0], c0, 0, 0, 0);
            c0 = __builtin_amdgcn_mfma_f32_16x16x32_bf16(a1, bfrag[0][1], c0, 0, 0, 0);
            if (LAYER > 0) {
                c1 = __builtin_amdgcn_mfma_f32_16x16x32_bf16(a0, bfrag[1][0], c1, 0, 0, 0);
                c1 = __builtin_amdgcn_mfma_f32_16x16x32_bf16(a1, bfrag[1][1], c1, 0, 0, 0);
            }
            c2 = __builtin_amdgcn_mfma_f32_16x16x32_bf16(a0, bfrag[2][0], c2, 0, 0, 0);
            c2 = __builtin_amdgcn_mfma_f32_16x16x32_bf16(a1, bfrag[2][1], c2, 0, 0, 0);

            float sN[4]; float4 vN[4];
            if (mt < 7) {
#pragma unroll
                for (int reg = 0; reg < 4; ++reg) {
                    const int j = (mt + 1) * 16 + jsub + reg;
                    sN[reg] = sb[j * FF + f];
                    if (LAYER > 0) vN[reg] = vb4[j * FF + f];
                }
            }
#pragma unroll
            for (int reg = 0; reg < 4; ++reg) {
                const int j  = mt * 16 + jsub + reg;
                const float r1 = c0[reg];
                const float r2 = c1[reg];
                const float r3 = c2[reg];
                const float sj = sP[reg];
                const float r3s = r3 * sj;
                const float4 u = unitr[j];
                accs = fmaf(r1, sj, accs);
                av0 = fmaf(r3s, u.x, av0);
                av1 = fmaf(r3s, u.y, av1);
                av2 = fmaf(r3s, u.z, av2);
                if (LAYER > 0) {
                    av0 = fmaf(r2, vP[reg].x, av0);
                    av1 = fmaf(r2, vP[reg].y, av1);
                    av2 = fmaf(r2, vP[reg].z, av2);
                }
            }
#pragma unroll
            for (int reg = 0; reg < 4; ++reg) {
                sP[reg] = sN[reg];
                if (LAYER > 0) vP[reg] = vN[reg];
            }
        }
        accs += __shfl_xor(accs, 16, 64); accs += __shfl_xor(accs, 32, 64);
        av0  += __shfl_xor(av0, 16, 64);  av0  += __shfl_xor(av0, 32, 64);
        av1  += __shfl_xor(av1, 16, 64);  av1  += __shfl_xor(av1, 32, 64);
        av2  += __shfl_xor(av2, 16, 64);  av2  += __shfl_xor(av2, 32, 64);
        if (l < 16) {
            ((float*)agg4)[0 * 64 + f] = accs;   // 1/127 folded into W2
            ((float*)agg4)[1 * 64 + f] = av0;
            ((float*)agg4)[2 * 64 + f] = av1;
            ((float*)agg4)[3 * 64 + f] = av2;
        }
    };

    // TAIL: node update (+ readout) for receiver ie; reads agg4.
    auto TAIL = [&](int ie) {
        const int g = l;
        const int node = b * NN + ie;
        const float4* wv4 = (const float4*)wT4;
        if (LAYER == 0) {
            const int m = (w == 0) ? 0 : 1;
            const int row = (w == 0) ? 0 : w;
            float a = (w == 0) ? s_in[node * FF + g] : 0.0f;
#pragma unroll
            for (int k = 0; k < 16; ++k) {
                const float4 w4 = wv4[(m * 16 + k) * 64 + g];
                const float4 a4 = agg4[row][k];
                a = fmaf(a4.x, w4.x, a); a = fmaf(a4.y, w4.y, a);
                a = fmaf(a4.z, w4.z, a); a = fmaf(a4.w, w4.w, a);
            }
            if (w == 0) s_out[node * FF + g] = a;
            else        v_out[(node * FF + g) * 4 + (w - 1)] = a;
        } else {
            if (w > 0) {
                const int d = w - 1;
                float a = v_in[(node * FF + g) * 4 + d];
#pragma unroll
                for (int k = 0; k < 16; ++k) {
                    const float4 w4 = wv4[(16 + k) * 64 + g];
                    const float4 a4 = agg4[w][k];
                    a = fmaf(a4.x, w4.x, a); a = fmaf(a4.y, w4.y, a);
                    a = fmaf(a4.z, w4.z, a); a = fmaf(a4.w, w4.w, a);
                }
                float p = a * wout[g];
#pragma unroll
                for (int off = 1; off < 64; off <<= 1)
                    p += __shfl_xor(p, off, 64);
                if (l == 0)
                    out[node * 3 + d] = (p - pos[node * 3 + d]) * scale[0];
            }
        }
    };

    // ================= pipeline over 4 receivers ===========================
    A1(i0, 0);
    __syncthreads();
    A2(0);
    __syncthreads();
#pragma unroll
    for (int it = 0; it < 4; ++it) {
        const int cur = it & 1;
        // interval 1: A1(next) || BC(cur) -> agg
        if (it < 3) A1(i0 + it + 1, cur ^ 1);
        BC(cur);
        __syncthreads();
        // interval 2: A2(next) || TAIL(cur)
        if (it < 3) A2(cur ^ 1);
        TAIL(i0 + it);
        __syncthreads();
    }
}

extern "C" void kernel_launch(void* const* d_in, const int* in_sizes, int n_in,
                              void* d_out, int out_size, void* d_ws, size_t ws_size,
                              hipStream_t stream) {
    const float* pos     = (const float*)d_in[0];
    const int*   species = (const int*)  d_in[1];
    const float* glob    = (const float*)d_in[2];
    const float* embed   = (const float*)d_in[3];
    const float* glob_w  = (const float*)d_in[4];
    const float* rbf_w1  = (const float*)d_in[5];   // [2][8][64]
    const float* rbf_b1  = (const float*)d_in[6];   // [2][64]
    const float* rbf_w2  = (const float*)d_in[7];   // [2][64][192]
    const float* ws      = (const float*)d_in[8];   // [2][64][64]
    const float* wv      = (const float*)d_in[9];   // [2][64][64]
    const float* wout    = (const float*)d_in[10];  // [64]
    const float* scale   = (const float*)d_in[11];  // [1]

    float* wsf = (float*)d_ws;
    float* s0     = wsf;                        // 262144 floats
    float* s1     = wsf + 262144;               // 262144
    float* v1     = wsf + 524288;               // 1048576
    short* w2frag = (short*)(wsf + 1572864);    // 24576 shorts (12288 floats)
    float* wT4    = wsf + 1585152;              // 16384 floats
    _Float16* w1A = (_Float16*)(wsf + 1601536); // 2048 halfs (1024 floats)
    float* outp = (float*)d_out;

    setup_kernel<<<dim3(192 + BB * NN / 4), 256, 0, stream>>>(
        rbf_w2, ws, wv, rbf_w1, rbf_b1, species, glob, embed, glob_w,
        w2frag, wT4, w1A, s0);

    msg_kernel<0><<<dim3(NN * BB / 4), 256, 0, stream>>>(
        pos, s0, nullptr,
        (const half4*)w1A, w2frag, wT4, wout, scale,
        s1, v1, nullptr);

    msg_kernel<1><<<dim3(NN * BB / 4), 256, 0, stream>>>(
        pos, s1, v1,
        (const half4*)(w1A + 1024), w2frag + 12288, wT4 + 8192, wout, scale,
        nullptr, nullptr, outp);
}

// Round 17
// 78.349 us; speedup vs baseline: 1.3920x; 1.3920x over previous
//
#include <hip/hip_runtime.h>
#include <hip/hip_bf16.h>

// MACE-like GNN on MI355X — MFMA for BOTH GEMMs.
// B=32, N=128, F=64, N_RBF=8, H_R=64, L=2.
// Round 17: revert to round-14 structure (best: 78.9us). R15/R16 proved the
// kernel is issue-throughput-bound, not residency-bound (R16's lambda pipeline
// spilled: VGPR 128, 41MB scratch). One micro: tile-0 s/v prefetch hoisted
// above A1 so L2 latency hides under A1/A2.

#define NN 128
#define BB 32
#define FF 64

using f32x4  = __attribute__((ext_vector_type(4))) float;
using short8 = __attribute__((ext_vector_type(8))) short;
using half4  = __attribute__((ext_vector_type(4))) _Float16;

__device__ __forceinline__ unsigned short f2bf(float x) {
    unsigned int u = __float_as_uint(x);
    u += 0x7fff + ((u >> 16) & 1);          // RNE
    return (unsigned short)(u >> 16);
}
__device__ __forceinline__ unsigned int f2bf_fast32(float x) {
    return (__float_as_uint(x) + 0x8000u) >> 16;
}

// -------------------- setup: bake weights + init node scalars --------------
__global__ __launch_bounds__(256) void setup_kernel(
    const float* __restrict__ w2,     // [2][64][192]
    const float* __restrict__ ws,     // [2][64][64]
    const float* __restrict__ wv,     // [2][64][64]
    const float* __restrict__ rbf_w1, // [2][8][64]
    const float* __restrict__ rbf_b1, // [2][64]
    const int* __restrict__ species, const float* __restrict__ glob,
    const float* __restrict__ embed, const float* __restrict__ glob_w,
    short* __restrict__ w2frag,       // [2][4][3][2][64][8] = 24576 shorts
    float* __restrict__ wT4,          // [2][2][16][64][4]   = 16384 floats
    _Float16* __restrict__ w1A,       // [2][4][64][4]       = 2048 halfs
    float* __restrict__ s)            // [B*N][64]
{
    const int blk = blockIdx.x;
    if (blk < 192) {
        const int tid = blk * 256 + threadIdx.x;
        const int NFRAG = 24576;
        if (tid < NFRAG) {
            const int e  = tid & 7;
            const int l  = (tid >> 3) & 63;
            const int ks = (tid >> 9) & 1;
            const int q  = tid >> 10;          // layer*12 + wave*3 + nt
            const int nt = q % 3;
            const int wv_ = (q / 3) & 3;
            const int layer = q / 12;
            const int col = nt * 64 + wv_ * 16 + (l & 15);
            const int hb  = ks * 32 + (l >> 4) * 8 + e;
            const float val = w2[layer * 64 * 192 + hb * 192 + col] * (1.0f / 127.0f);
            w2frag[tid] = (short)f2bf(val);
        }
        const int tid2 = tid - NFRAG;
        if (tid2 >= 0 && tid2 < 16384) {
            const int c   = tid2 & 3;
            const int g   = (tid2 >> 2) & 63;
            const int ff4 = (tid2 >> 8) & 15;
            const int m   = (tid2 >> 12) & 1;
            const int layer = tid2 >> 13;
            const float* src = (m == 0 ? ws : wv) + layer * 4096;
            wT4[tid2] = src[(ff4 * 4 + c) * 64 + g];
        }
        const int tid3 = tid - NFRAG - 16384;
        if (tid3 >= 0 && tid3 < 2048) {
            // A-frag 16x16x16: lane l holds A[row=l&15][k=(l>>4)*4+e]
            const int e  = tid3 & 3;
            const int l  = (tid3 >> 2) & 63;
            const int wv_ = (tid3 >> 8) & 3;
            const int layer = tid3 >> 10;
            const int k = (l >> 4) * 4 + e;
            const int h = wv_ * 16 + (l & 15);
            float val = 0.0f;
            if (k < 8)       val = rbf_w1[layer * 512 + k * 64 + h];
            else if (k == 8) val = rbf_b1[layer * 64 + h];
            w1A[tid3] = (_Float16)val;
        }
    } else {
        const int node = (blk - 192) * 4 + (threadIdx.x >> 6);   // b*128 + n
        const int b = node >> 7;
        const int f = threadIdx.x & 63;
        const int sp = species[node];
        float acc = embed[sp * FF + f];
#pragma unroll
        for (int k = 0; k < 16; ++k)
            acc = fmaf(glob[b * 16 + k], glob_w[k * FF + f], acc);
        s[node * FF + f] = acc;
    }
}

// -------------------- fused message+agg+update (+readout for LAYER==1) ----
// grid 4096 (XCD-swizzled), block 256 = 4 waves.
// wave w owns channels f in [16w, 16w+16).
template<int LAYER>
__global__ __launch_bounds__(256, 2) void msg_kernel(
    const float* __restrict__ pos,     // [B][N][3]
    const float* __restrict__ s_in,    // [B][N][F]
    const float* __restrict__ v_in,    // [B][N][F][4]  (unused when LAYER==0)
    const half4* __restrict__ w1Abuf,  // [4][64] half4 (layer slice)
    const short* __restrict__ w2frag,  // [4][3][2][64][8] bf16 (layer slice)
    const float* __restrict__ wT4,     // [2][16][64][4] (ws,wv; layer slice)
    const float* __restrict__ wout,    // [64]
    const float* __restrict__ scale,   // [1]
    float* __restrict__ s_out,         // LAYER==0 only
    float* __restrict__ v_out,         // LAYER==0 only, [B][N][F][4]
    float* __restrict__ out)           // LAYER==1 only
{
    __shared__ unsigned short hid_lds[NN * 64];       // 16 KB, XOR-swizzled rows
    __shared__ float4 unit_lds[NN];                   // 2 KB
    __shared__ __align__(16) char phi_pool[NN * 32];  // 4 KB; agg4 alias after A2
    float4 (*agg4)[16] = (float4(*)[16])phi_pool;

    // XCD-aware swizzle: 4 consecutive batches per XCD -> L2-resident s/v.
    const int blk = blockIdx.x;
    const int xcd = blk & 7;
    const int idx = blk >> 3;            // 0..511
    const int b = xcd * 4 + (idx >> 7);
    const int i = idx & 127;

    const int t = threadIdx.x;
    const int w = t >> 6;          // wave
    const int l = t & 63;          // lane
    const int node = b * NN + i;
    const float* pb = pos + b * NN * 3;

    const int f    = w * 16 + (l & 15);
    const int jsub = (l >> 4) * 4;
    const float* sb = s_in + b * NN * FF;
    const float4* vb4 = (LAYER > 0) ? ((const float4*)v_in) + b * NN * FF : nullptr;

    // ---- hoisted tile-0 s/v prefetch: L2 latency hides under A1/A2 ----
    float sP[4]; float4 vP[4];
#pragma unroll
    for (int reg = 0; reg < 4; ++reg) {
        const int j = jsub + reg;
        sP[reg] = sb[j * FF + f];
        if (LAYER > 0) vP[reg] = vb4[j * FF + f];
    }

    // ---- B fragments (W2), pre-baked; r2 frag unused in layer 0 ----
    short8 bfrag[3][2];
    {
        const short8* wf = (const short8*)w2frag;
#pragma unroll
        for (int nt = 0; nt < 3; ++nt) {
            if (LAYER == 0 && nt == 1) continue;
#pragma unroll
            for (int ks = 0; ks < 2; ++ks)
                bfrag[nt][ks] = wf[((w * 3 + nt) * 2 + ks) * 64 + l];
        }
    }

    // ---- phase A1: distance/unit + phi (f16 rows [128][16], K=16 layout) ---
    {
        const int j = t & 127;
        const int half = t >> 7;
        const float dx = pb[i * 3 + 0] - pb[j * 3 + 0];
        const float dy = pb[i * 3 + 1] - pb[j * 3 + 1];
        const float dz = pb[i * 3 + 2] - pb[j * 3 + 2];
        const float d2 = fmaf(dx, dx, fmaf(dy, dy, fmaf(dz, dz, 1e-12f)));
        const float inv = __builtin_amdgcn_rsqf(d2);
        const float dd = d2 * inv;
        if (half == 0)
            unit_lds[j] = make_float4(dx * inv, dy * inv, dz * inv, 0.0f);
        const _Float16 zf = (_Float16)0.f;
        half4 ph;
#pragma unroll
        for (int r = 0; r < 4; ++r) {
            const float td = dd - (float)(half * 4 + r) * (5.0f / 7.0f);
            ph[r] = (_Float16)__expf(td * td * -1.28f);   // 1/(2*0.625^2)
        }
        if (j == i) ph = (half4){zf, zf, zf, zf};
        char* rowp = phi_pool + j * 32;
        const int swz = ((j >> 2) & 3) << 3;
        *(half4*)(rowp + ((half * 8) ^ swz)) = ph;
        if (half == 0) {
            half4 bias = {(j == i) ? zf : (_Float16)1.0f, zf, zf, zf};
            *(half4*)(rowp + (16 ^ swz)) = bias;          // k=8..11
        } else {
            *(half4*)(rowp + (24 ^ swz)) = (half4){zf, zf, zf, zf}; // k=12..15
        }
    }
    __syncthreads();

    // ---- phase A2: pre[h,j] = mfma(W1^T, phi^T); silu -> hid_lds (b64) ----
    {
        const half4 w1a = w1Abuf[w * 64 + l];
        const int jcol = l & 15;
        const int chunk = (l >> 4) * 8;
        const int hbyte = w * 32 + (l >> 4) * 8;   // h = w*16 + (l>>4)*4 + reg
#pragma unroll
        for (int mt = 0; mt < 8; ++mt) {
            const int j = mt * 16 + jcol;
            const half4 bphi = *(const half4*)(
                phi_pool + j * 32 + (chunk ^ (((j >> 2) & 3) << 3)));
            f32x4 pre = __builtin_amdgcn_mfma_f32_16x16x16f16(
                w1a, bphi, (f32x4){0.f, 0.f, 0.f, 0.f}, 0, 0, 0);
            unsigned int pk[2];
#pragma unroll
            for (int p = 0; p < 2; ++p) {
                float sv[2];
#pragma unroll
                for (int q = 0; q < 2; ++q) {
                    const float z = pre[p * 2 + q];
                    const float ex = __expf(-z);
                    sv[q] = z * __builtin_amdgcn_rcpf(1.0f + ex);
                }
                pk[p] = f2bf_fast32(sv[0]) | (f2bf_fast32(sv[1]) << 16);
            }
            const int byte = j * 128 + (hbyte ^ ((j & 7) << 4));
            *(uint2*)((char*)hid_lds + byte) = make_uint2(pk[0], pk[1]);
        }
    }
    __syncthreads();

    // ---- fused phase B+C: per 16-row j-tile, MFMA then consume ----
    float accs = 0.f, av0 = 0.f, av1 = 0.f, av2 = 0.f;

#pragma unroll
    for (int mt = 0; mt < 8; ++mt) {
        const int jA = mt * 16 + (l & 15);
        const int base = jA * 128;
        const int sw = (jA & 7) << 4;
        const short8 a0 = *(const short8*)((const char*)hid_lds + base + (((l >> 4) * 16 +  0) ^ sw));
        const short8 a1 = *(const short8*)((const char*)hid_lds + base + (((l >> 4) * 16 + 64) ^ sw));

        f32x4 c0 = (f32x4){0.f, 0.f, 0.f, 0.f};
        f32x4 c1 = (f32x4){0.f, 0.f, 0.f, 0.f};
        f32x4 c2 = (f32x4){0.f, 0.f, 0.f, 0.f};
        c0 = __builtin_amdgcn_mfma_f32_16x16x32_bf16(a0, bfrag[0][0], c0, 0, 0, 0);
        c0 = __builtin_amdgcn_mfma_f32_16x16x32_bf16(a1, bfrag[0][1], c0, 0, 0, 0);
        if (LAYER > 0) {
            c1 = __builtin_amdgcn_mfma_f32_16x16x32_bf16(a0, bfrag[1][0], c1, 0, 0, 0);
            c1 = __builtin_amdgcn_mfma_f32_16x16x32_bf16(a1, bfrag[1][1], c1, 0, 0, 0);
        }
        c2 = __builtin_amdgcn_mfma_f32_16x16x32_bf16(a0, bfrag[2][0], c2, 0, 0, 0);
        c2 = __builtin_amdgcn_mfma_f32_16x16x32_bf16(a1, bfrag[2][1], c2, 0, 0, 0);

        float sN[4]; float4 vN[4];
        if (mt < 7) {
#pragma unroll
            for (int reg = 0; reg < 4; ++reg) {
                const int j = (mt + 1) * 16 + jsub + reg;
                sN[reg] = sb[j * FF + f];
                if (LAYER > 0) vN[reg] = vb4[j * FF + f];
            }
        }

#pragma unroll
        for (int reg = 0; reg < 4; ++reg) {
            const int j  = mt * 16 + jsub + reg;
            const float r1 = c0[reg];
            const float r2 = c1[reg];
            const float r3 = c2[reg];
            const float sj = sP[reg];
            const float r3s = r3 * sj;
            const float4 u = unit_lds[j];
            accs = fmaf(r1, sj, accs);
            av0 = fmaf(r3s, u.x, av0);
            av1 = fmaf(r3s, u.y, av1);
            av2 = fmaf(r3s, u.z, av2);
            if (LAYER > 0) {
                av0 = fmaf(r2, vP[reg].x, av0);
                av1 = fmaf(r2, vP[reg].y, av1);
                av2 = fmaf(r2, vP[reg].z, av2);
            }
        }
#pragma unroll
        for (int reg = 0; reg < 4; ++reg) {
            sP[reg] = sN[reg];
            if (LAYER > 0) vP[reg] = vN[reg];
        }
    }

    accs += __shfl_xor(accs, 16, 64); accs += __shfl_xor(accs, 32, 64);
    av0  += __shfl_xor(av0, 16, 64);  av0  += __shfl_xor(av0, 32, 64);
    av1  += __shfl_xor(av1, 16, 64);  av1  += __shfl_xor(av1, 32, 64);
    av2  += __shfl_xor(av2, 16, 64);  av2  += __shfl_xor(av2, 32, 64);
    if (l < 16) {
        // 1/127 already folded into W2 fragments; phi_pool dead -> agg4 alias OK
        ((float*)agg4)[0 * 64 + f] = accs;
        ((float*)agg4)[1 * 64 + f] = av0;
        ((float*)agg4)[2 * 64 + f] = av1;
        ((float*)agg4)[3 * 64 + f] = av2;
    }
    __syncthreads();

    // ---- tail: node update (+ readout for last layer), coalesced wT4 ------
    // wT4 layout: [m][ff4][g][4]; lane g loads float4 at (m*16+ff4)*64+g.
    const int g = l;
    const float4* wv4 = (const float4*)wT4;
    if (LAYER == 0) {
        const int m = (w == 0) ? 0 : 1;
        const int row = (w == 0) ? 0 : w;
        float a = (w == 0) ? s_in[node * FF + g] : 0.0f;
#pragma unroll
        for (int k = 0; k < 16; ++k) {
            const float4 w4 = wv4[(m * 16 + k) * 64 + g];
            const float4 a4 = agg4[row][k];
            a = fmaf(a4.x, w4.x, a); a = fmaf(a4.y, w4.y, a);
            a = fmaf(a4.z, w4.z, a); a = fmaf(a4.w, w4.w, a);
        }
        if (w == 0) s_out[node * FF + g] = a;
        else        v_out[(node * FF + g) * 4 + (w - 1)] = a;
    } else {
        if (w > 0) {
            const int d = w - 1;
            float a = v_in[(node * FF + g) * 4 + d];
#pragma unroll
            for (int k = 0; k < 16; ++k) {
                const float4 w4 = wv4[(16 + k) * 64 + g];
                const float4 a4 = agg4[w][k];
                a = fmaf(a4.x, w4.x, a); a = fmaf(a4.y, w4.y, a);
                a = fmaf(a4.z, w4.z, a); a = fmaf(a4.w, w4.w, a);
            }
            float p = a * wout[g];
#pragma unroll
            for (int off = 1; off < 64; off <<= 1)
                p += __shfl_xor(p, off, 64);
            if (l == 0)
                out[node * 3 + d] = (p - pos[node * 3 + d]) * scale[0];
        }
    }
}

extern "C" void kernel_launch(void* const* d_in, const int* in_sizes, int n_in,
                              void* d_out, int out_size, void* d_ws, size_t ws_size,
                              hipStream_t stream) {
    const float* pos     = (const float*)d_in[0];
    const int*   species = (const int*)  d_in[1];
    const float* glob    = (const float*)d_in[2];
    const float* embed   = (const float*)d_in[3];
    const float* glob_w  = (const float*)d_in[4];
    const float* rbf_w1  = (const float*)d_in[5];   // [2][8][64]
    const float* rbf_b1  = (const float*)d_in[6];   // [2][64]
    const float* rbf_w2  = (const float*)d_in[7];   // [2][64][192]
    const float* ws      = (const float*)d_in[8];   // [2][64][64]
    const float* wv      = (const float*)d_in[9];   // [2][64][64]
    const float* wout    = (const float*)d_in[10];  // [64]
    const float* scale   = (const float*)d_in[11];  // [1]

    float* wsf = (float*)d_ws;
    float* s0     = wsf;                        // 262144 floats
    float* s1     = wsf + 262144;               // 262144
    float* v1     = wsf + 524288;               // 1048576
    short* w2frag = (short*)(wsf + 1572864);    // 24576 shorts (12288 floats)
    float* wT4    = wsf + 1585152;              // 16384 floats
    _Float16* w1A = (_Float16*)(wsf + 1601536); // 2048 halfs (1024 floats)
    float* outp = (float*)d_out;

    setup_kernel<<<dim3(192 + BB * NN / 4), 256, 0, stream>>>(
        rbf_w2, ws, wv, rbf_w1, rbf_b1, species, glob, embed, glob_w,
        w2frag, wT4, w1A, s0);

    msg_kernel<0><<<dim3(NN * BB), 256, 0, stream>>>(
        pos, s0, nullptr,
        (const half4*)w1A, w2frag, wT4, wout, scale,
        s1, v1, nullptr);

    msg_kernel<1><<<dim3(NN * BB), 256, 0, stream>>>(
        pos, s1, v1,
        (const half4*)(w1A + 1024), w2frag + 12288, wT4 + 8192, wout, scale,
        nullptr, nullptr, outp);
}

// Round 18
// 67.705 us; speedup vs baseline: 1.6109x; 1.1572x over previous
//
#include <hip/hip_runtime.h>
#include <hip/hip_bf16.h>

// MACE-like GNN on MI355X — MFMA both GEMMs, 2 receivers per block.
// B=32, N=128, F=64, N_RBF=8, H_R=64, L=2.
// Round 18: one block serves receivers {i0,i0+1} SEQUENTIALLY (no lambda
// pipeline — R16 lesson). Shared across receivers: s/v register loads in BC,
// wT4 loads in tail, bfrag/w1A, and barriers (3 per 2 receivers).

#define NN 128
#define BB 32
#define FF 64

using f32x4  = __attribute__((ext_vector_type(4))) float;
using short8 = __attribute__((ext_vector_type(8))) short;
using half4  = __attribute__((ext_vector_type(4))) _Float16;

__device__ __forceinline__ unsigned short f2bf(float x) {
    unsigned int u = __float_as_uint(x);
    u += 0x7fff + ((u >> 16) & 1);          // RNE
    return (unsigned short)(u >> 16);
}
__device__ __forceinline__ unsigned int f2bf_fast32(float x) {
    return (__float_as_uint(x) + 0x8000u) >> 16;
}

// -------------------- setup: bake weights + init node scalars --------------
__global__ __launch_bounds__(256) void setup_kernel(
    const float* __restrict__ w2,     // [2][64][192]
    const float* __restrict__ ws,     // [2][64][64]
    const float* __restrict__ wv,     // [2][64][64]
    const float* __restrict__ rbf_w1, // [2][8][64]
    const float* __restrict__ rbf_b1, // [2][64]
    const int* __restrict__ species, const float* __restrict__ glob,
    const float* __restrict__ embed, const float* __restrict__ glob_w,
    short* __restrict__ w2frag,       // [2][4][3][2][64][8] = 24576 shorts
    float* __restrict__ wT4,          // [2][2][16][64][4]   = 16384 floats
    _Float16* __restrict__ w1A,       // [2][4][64][4]       = 2048 halfs
    float* __restrict__ s)            // [B*N][64]
{
    const int blk = blockIdx.x;
    if (blk < 192) {
        const int tid = blk * 256 + threadIdx.x;
        const int NFRAG = 24576;
        if (tid < NFRAG) {
            const int e  = tid & 7;
            const int l  = (tid >> 3) & 63;
            const int ks = (tid >> 9) & 1;
            const int q  = tid >> 10;          // layer*12 + wave*3 + nt
            const int nt = q % 3;
            const int wv_ = (q / 3) & 3;
            const int layer = q / 12;
            const int col = nt * 64 + wv_ * 16 + (l & 15);
            const int hb  = ks * 32 + (l >> 4) * 8 + e;
            const float val = w2[layer * 64 * 192 + hb * 192 + col] * (1.0f / 127.0f);
            w2frag[tid] = (short)f2bf(val);
        }
        const int tid2 = tid - NFRAG;
        if (tid2 >= 0 && tid2 < 16384) {
            const int c   = tid2 & 3;
            const int g   = (tid2 >> 2) & 63;
            const int ff4 = (tid2 >> 8) & 15;
            const int m   = (tid2 >> 12) & 1;
            const int layer = tid2 >> 13;
            const float* src = (m == 0 ? ws : wv) + layer * 4096;
            wT4[tid2] = src[(ff4 * 4 + c) * 64 + g];
        }
        const int tid3 = tid - NFRAG - 16384;
        if (tid3 >= 0 && tid3 < 2048) {
            // A-frag 16x16x16: lane l holds A[row=l&15][k=(l>>4)*4+e]
            const int e  = tid3 & 3;
            const int l  = (tid3 >> 2) & 63;
            const int wv_ = (tid3 >> 8) & 3;
            const int layer = tid3 >> 10;
            const int k = (l >> 4) * 4 + e;
            const int h = wv_ * 16 + (l & 15);
            float val = 0.0f;
            if (k < 8)       val = rbf_w1[layer * 512 + k * 64 + h];
            else if (k == 8) val = rbf_b1[layer * 64 + h];
            w1A[tid3] = (_Float16)val;
        }
    } else {
        const int node = (blk - 192) * 4 + (threadIdx.x >> 6);   // b*128 + n
        const int b = node >> 7;
        const int f = threadIdx.x & 63;
        const int sp = species[node];
        float acc = embed[sp * FF + f];
#pragma unroll
        for (int k = 0; k < 16; ++k)
            acc = fmaf(glob[b * 16 + k], glob_w[k * FF + f], acc);
        s[node * FF + f] = acc;
    }
}

// -------------------- fused message+agg+update, 2 receivers/block ---------
// grid 2048 (XCD-swizzled), block 256 = 4 waves; wave w owns f in [16w,16w+16).
template<int LAYER>
__global__ __launch_bounds__(256, 2) void msg_kernel(
    const float* __restrict__ pos,     // [B][N][3]
    const float* __restrict__ s_in,    // [B][N][F]
    const float* __restrict__ v_in,    // [B][N][F][4]  (unused when LAYER==0)
    const half4* __restrict__ w1Abuf,  // [4][64] half4 (layer slice)
    const short* __restrict__ w2frag,  // [4][3][2][64][8] bf16 (layer slice)
    const float* __restrict__ wT4,     // [2][16][64][4] (ws,wv; layer slice)
    const float* __restrict__ wout,    // [64]
    const float* __restrict__ scale,   // [1]
    float* __restrict__ s_out,         // LAYER==0 only
    float* __restrict__ v_out,         // LAYER==0 only, [B][N][F][4]
    float* __restrict__ out)           // LAYER==1 only
{
    __shared__ unsigned short hid_lds[2 * NN * 64];       // 32 KB
    __shared__ float4 unit_lds[2][NN];                    // 4 KB
    __shared__ __align__(16) char phi_pool[2 * NN * 32];  // 8 KB; agg alias
    // after A2, phi_pool is dead: agg floats at [rr*256 + m*64 + f]

    // XCD-aware swizzle: 4 consecutive batches per XCD -> L2-resident s/v.
    const int blk = blockIdx.x;
    const int xcd = blk & 7;
    const int idx = blk >> 3;            // 0..255
    const int b = xcd * 4 + (idx >> 6);
    const int i0 = (idx & 63) * 2;       // receivers i0, i0+1

    const int t = threadIdx.x;
    const int w = t >> 6;          // wave
    const int l = t & 63;          // lane
    const float* pb = pos + b * NN * 3;

    const int f    = w * 16 + (l & 15);
    const int jsub = (l >> 4) * 4;
    const float* sb = s_in + b * NN * FF;
    const float4* vb4 = (LAYER > 0) ? ((const float4*)v_in) + b * NN * FF : nullptr;

    // ---- hoisted tile-0 s/v prefetch (receiver-independent) ----
    float sP[4]; float4 vP[4];
#pragma unroll
    for (int reg = 0; reg < 4; ++reg) {
        const int j = jsub + reg;
        sP[reg] = sb[j * FF + f];
        if (LAYER > 0) vP[reg] = vb4[j * FF + f];
    }

    // ---- B fragments (W2), pre-baked; r2 frag unused in layer 0 ----
    short8 bfrag[3][2];
    {
        const short8* wf = (const short8*)w2frag;
#pragma unroll
        for (int nt = 0; nt < 3; ++nt) {
            if (LAYER == 0 && nt == 1) continue;
#pragma unroll
            for (int ks = 0; ks < 2; ++ks)
                bfrag[nt][ks] = wf[((w * 3 + nt) * 2 + ks) * 64 + l];
        }
    }

    // ---- phase A1: distance/unit + phi for BOTH receivers ----
    // thread t -> (rr = t>>7, j = t&127); full 8-gaussian row per thread.
    {
        const int j = t & 127;
        const int rr = t >> 7;
        const int ie = i0 + rr;
        const float dx = pb[ie * 3 + 0] - pb[j * 3 + 0];
        const float dy = pb[ie * 3 + 1] - pb[j * 3 + 1];
        const float dz = pb[ie * 3 + 2] - pb[j * 3 + 2];
        const float d2 = fmaf(dx, dx, fmaf(dy, dy, fmaf(dz, dz, 1e-12f)));
        const float inv = __builtin_amdgcn_rsqf(d2);
        const float dd = d2 * inv;
        unit_lds[rr][j] = make_float4(dx * inv, dy * inv, dz * inv, 0.0f);
        const _Float16 zf = (_Float16)0.f;
        const half4 z4 = {zf, zf, zf, zf};
        half4 ph0, ph1;
#pragma unroll
        for (int r = 0; r < 4; ++r) {
            const float td0 = dd - (float)r * (5.0f / 7.0f);
            ph0[r] = (_Float16)__expf(td0 * td0 * -1.28f);   // 1/(2*0.625^2)
            const float td1 = dd - (float)(4 + r) * (5.0f / 7.0f);
            ph1[r] = (_Float16)__expf(td1 * td1 * -1.28f);
        }
        if (j == ie) { ph0 = z4; ph1 = z4; }
        char* rowp = phi_pool + rr * 4096 + j * 32;
        const int swz = ((j >> 2) & 3) << 3;
        *(half4*)(rowp + (0 ^ swz))  = ph0;
        *(half4*)(rowp + (8 ^ swz))  = ph1;
        half4 bias = {(j == ie) ? zf : (_Float16)1.0f, zf, zf, zf};
        *(half4*)(rowp + (16 ^ swz)) = bias;                 // k=8..11
        *(half4*)(rowp + (24 ^ swz)) = z4;                   // k=12..15
    }
    __syncthreads();

    // ---- phase A2: both receivers; pre[h,j] = mfma(W1^T, phi^T) ----
    {
        const half4 w1a = w1Abuf[w * 64 + l];
        const int jcol = l & 15;
        const int chunk = (l >> 4) * 8;
        const int hbyte = w * 32 + (l >> 4) * 8;   // h = w*16 + (l>>4)*4 + reg
#pragma unroll
        for (int rr = 0; rr < 2; ++rr) {
            const char* phir = phi_pool + rr * 4096;
            char* hidr = (char*)hid_lds + rr * 16384;
#pragma unroll
            for (int mt = 0; mt < 8; ++mt) {
                const int j = mt * 16 + jcol;
                const half4 bphi = *(const half4*)(
                    phir + j * 32 + (chunk ^ (((j >> 2) & 3) << 3)));
                f32x4 pre = __builtin_amdgcn_mfma_f32_16x16x16f16(
                    w1a, bphi, (f32x4){0.f, 0.f, 0.f, 0.f}, 0, 0, 0);
                unsigned int pk[2];
#pragma unroll
                for (int p = 0; p < 2; ++p) {
                    float sv[2];
#pragma unroll
                    for (int q = 0; q < 2; ++q) {
                        const float z = pre[p * 2 + q];
                        const float ex = __expf(-z);
                        sv[q] = z * __builtin_amdgcn_rcpf(1.0f + ex);
                    }
                    pk[p] = f2bf_fast32(sv[0]) | (f2bf_fast32(sv[1]) << 16);
                }
                const int byte = j * 128 + (hbyte ^ ((j & 7) << 4));
                *(uint2*)(hidr + byte) = make_uint2(pk[0], pk[1]);
            }
        }
    }
    __syncthreads();

    // ---- fused phase B+C: per j-tile, MFMA+consume for BOTH receivers ----
    // s/v registers shared across receivers (receiver-independent).
    float a0s = 0.f, a0x = 0.f, a0y = 0.f, a0z = 0.f;
    float a1s = 0.f, a1x = 0.f, a1y = 0.f, a1z = 0.f;

#pragma unroll
    for (int mt = 0; mt < 8; ++mt) {
        const int jA = mt * 16 + (l & 15);
        const int base = jA * 128;
        const int sw = (jA & 7) << 4;
        const int o0 = base + (((l >> 4) * 16 +  0) ^ sw);
        const int o1 = base + (((l >> 4) * 16 + 64) ^ sw);
        const char* hp = (const char*)hid_lds;
        const short8 a0r0 = *(const short8*)(hp + o0);
        const short8 a1r0 = *(const short8*)(hp + o1);
        const short8 a0r1 = *(const short8*)(hp + 16384 + o0);
        const short8 a1r1 = *(const short8*)(hp + 16384 + o1);

        // receiver 0 MFMAs
        f32x4 c0 = (f32x4){0.f, 0.f, 0.f, 0.f};
        f32x4 c1 = (f32x4){0.f, 0.f, 0.f, 0.f};
        f32x4 c2 = (f32x4){0.f, 0.f, 0.f, 0.f};
        c0 = __builtin_amdgcn_mfma_f32_16x16x32_bf16(a0r0, bfrag[0][0], c0, 0, 0, 0);
        c0 = __builtin_amdgcn_mfma_f32_16x16x32_bf16(a1r0, bfrag[0][1], c0, 0, 0, 0);
        if (LAYER > 0) {
            c1 = __builtin_amdgcn_mfma_f32_16x16x32_bf16(a0r0, bfrag[1][0], c1, 0, 0, 0);
            c1 = __builtin_amdgcn_mfma_f32_16x16x32_bf16(a1r0, bfrag[1][1], c1, 0, 0, 0);
        }
        c2 = __builtin_amdgcn_mfma_f32_16x16x32_bf16(a0r0, bfrag[2][0], c2, 0, 0, 0);
        c2 = __builtin_amdgcn_mfma_f32_16x16x32_bf16(a1r0, bfrag[2][1], c2, 0, 0, 0);

        // prefetch next tile's s/v (shared) while r0 MFMAs are in flight
        float sN[4]; float4 vN[4];
        if (mt < 7) {
#pragma unroll
            for (int reg = 0; reg < 4; ++reg) {
                const int j = (mt + 1) * 16 + jsub + reg;
                sN[reg] = sb[j * FF + f];
                if (LAYER > 0) vN[reg] = vb4[j * FF + f];
            }
        }

        // consume receiver 0
#pragma unroll
        for (int reg = 0; reg < 4; ++reg) {
            const int j  = mt * 16 + jsub + reg;
            const float sj = sP[reg];
            const float r3s = c2[reg] * sj;
            const float4 u = unit_lds[0][j];
            a0s = fmaf(c0[reg], sj, a0s);
            a0x = fmaf(r3s, u.x, a0x);
            a0y = fmaf(r3s, u.y, a0y);
            a0z = fmaf(r3s, u.z, a0z);
            if (LAYER > 0) {
                a0x = fmaf(c1[reg], vP[reg].x, a0x);
                a0y = fmaf(c1[reg], vP[reg].y, a0y);
                a0z = fmaf(c1[reg], vP[reg].z, a0z);
            }
        }

        // receiver 1 MFMAs (c-registers recycled — r0's are dead)
        c0 = (f32x4){0.f, 0.f, 0.f, 0.f};
        c1 = (f32x4){0.f, 0.f, 0.f, 0.f};
        c2 = (f32x4){0.f, 0.f, 0.f, 0.f};
        c0 = __builtin_amdgcn_mfma_f32_16x16x32_bf16(a0r1, bfrag[0][0], c0, 0, 0, 0);
        c0 = __builtin_amdgcn_mfma_f32_16x16x32_bf16(a1r1, bfrag[0][1], c0, 0, 0, 0);
        if (LAYER > 0) {
            c1 = __builtin_amdgcn_mfma_f32_16x16x32_bf16(a0r1, bfrag[1][0], c1, 0, 0, 0);
            c1 = __builtin_amdgcn_mfma_f32_16x16x32_bf16(a1r1, bfrag[1][1], c1, 0, 0, 0);
        }
        c2 = __builtin_amdgcn_mfma_f32_16x16x32_bf16(a0r1, bfrag[2][0], c2, 0, 0, 0);
        c2 = __builtin_amdgcn_mfma_f32_16x16x32_bf16(a1r1, bfrag[2][1], c2, 0, 0, 0);

        // consume receiver 1 (same sP/vP!)
#pragma unroll
        for (int reg = 0; reg < 4; ++reg) {
            const int j  = mt * 16 + jsub + reg;
            const float sj = sP[reg];
            const float r3s = c2[reg] * sj;
            const float4 u = unit_lds[1][j];
            a1s = fmaf(c0[reg], sj, a1s);
            a1x = fmaf(r3s, u.x, a1x);
            a1y = fmaf(r3s, u.y, a1y);
            a1z = fmaf(r3s, u.z, a1z);
            if (LAYER > 0) {
                a1x = fmaf(c1[reg], vP[reg].x, a1x);
                a1y = fmaf(c1[reg], vP[reg].y, a1y);
                a1z = fmaf(c1[reg], vP[reg].z, a1z);
            }
        }

#pragma unroll
        for (int reg = 0; reg < 4; ++reg) {
            sP[reg] = sN[reg];
            if (LAYER > 0) vP[reg] = vN[reg];
        }
    }

    // reduce (j-quarter lanes 16/32) for both receivers
    a0s += __shfl_xor(a0s, 16, 64); a0s += __shfl_xor(a0s, 32, 64);
    a0x += __shfl_xor(a0x, 16, 64); a0x += __shfl_xor(a0x, 32, 64);
    a0y += __shfl_xor(a0y, 16, 64); a0y += __shfl_xor(a0y, 32, 64);
    a0z += __shfl_xor(a0z, 16, 64); a0z += __shfl_xor(a0z, 32, 64);
    a1s += __shfl_xor(a1s, 16, 64); a1s += __shfl_xor(a1s, 32, 64);
    a1x += __shfl_xor(a1x, 16, 64); a1x += __shfl_xor(a1x, 32, 64);
    a1y += __shfl_xor(a1y, 16, 64); a1y += __shfl_xor(a1y, 32, 64);
    a1z += __shfl_xor(a1z, 16, 64); a1z += __shfl_xor(a1z, 32, 64);
    if (l < 16) {
        float* aggf = (float*)phi_pool;   // phi dead after A2; 1/127 in W2
        aggf[0 * 256 + 0 * 64 + f] = a0s;
        aggf[0 * 256 + 1 * 64 + f] = a0x;
        aggf[0 * 256 + 2 * 64 + f] = a0y;
        aggf[0 * 256 + 3 * 64 + f] = a0z;
        aggf[1 * 256 + 0 * 64 + f] = a1s;
        aggf[1 * 256 + 1 * 64 + f] = a1x;
        aggf[1 * 256 + 2 * 64 + f] = a1y;
        aggf[1 * 256 + 3 * 64 + f] = a1z;
    }
    __syncthreads();

    // ---- tail: node update (+ readout), wT4 loads shared across receivers --
    const int g = l;
    const int node0 = b * NN + i0;
    const int node1 = node0 + 1;
    const float4* wv4 = (const float4*)wT4;
    const float4* ag = (const float4*)phi_pool;   // [2][4][16] float4
    if (LAYER == 0) {
        const int m = (w == 0) ? 0 : 1;
        const int row = (w == 0) ? 0 : w;
        float a0 = (w == 0) ? s_in[node0 * FF + g] : 0.0f;
        float a1 = (w == 0) ? s_in[node1 * FF + g] : 0.0f;
#pragma unroll
        for (int k = 0; k < 16; ++k) {
            const float4 w4 = wv4[(m * 16 + k) * 64 + g];
            const float4 x0 = ag[0 * 64 + row * 16 + k];
            const float4 x1 = ag[1 * 64 + row * 16 + k];
            a0 = fmaf(x0.x, w4.x, a0); a0 = fmaf(x0.y, w4.y, a0);
            a0 = fmaf(x0.z, w4.z, a0); a0 = fmaf(x0.w, w4.w, a0);
            a1 = fmaf(x1.x, w4.x, a1); a1 = fmaf(x1.y, w4.y, a1);
            a1 = fmaf(x1.z, w4.z, a1); a1 = fmaf(x1.w, w4.w, a1);
        }
        if (w == 0) {
            s_out[node0 * FF + g] = a0;
            s_out[node1 * FF + g] = a1;
        } else {
            v_out[(node0 * FF + g) * 4 + (w - 1)] = a0;
            v_out[(node1 * FF + g) * 4 + (w - 1)] = a1;
        }
    } else {
        if (w > 0) {
            const int d = w - 1;
            float a0 = v_in[(node0 * FF + g) * 4 + d];
            float a1 = v_in[(node1 * FF + g) * 4 + d];
#pragma unroll
            for (int k = 0; k < 16; ++k) {
                const float4 w4 = wv4[(16 + k) * 64 + g];
                const float4 x0 = ag[0 * 64 + w * 16 + k];
                const float4 x1 = ag[1 * 64 + w * 16 + k];
                a0 = fmaf(x0.x, w4.x, a0); a0 = fmaf(x0.y, w4.y, a0);
                a0 = fmaf(x0.z, w4.z, a0); a0 = fmaf(x0.w, w4.w, a0);
                a1 = fmaf(x1.x, w4.x, a1); a1 = fmaf(x1.y, w4.y, a1);
                a1 = fmaf(x1.z, w4.z, a1); a1 = fmaf(x1.w, w4.w, a1);
            }
            const float wg = wout[g];
            float p0 = a0 * wg;
            float p1 = a1 * wg;
#pragma unroll
            for (int off = 1; off < 64; off <<= 1) {
                p0 += __shfl_xor(p0, off, 64);
                p1 += __shfl_xor(p1, off, 64);
            }
            if (l == 0) {
                const float sc = scale[0];
                out[node0 * 3 + d] = (p0 - pos[node0 * 3 + d]) * sc;
                out[node1 * 3 + d] = (p1 - pos[node1 * 3 + d]) * sc;
            }
        }
    }
}

extern "C" void kernel_launch(void* const* d_in, const int* in_sizes, int n_in,
                              void* d_out, int out_size, void* d_ws, size_t ws_size,
                              hipStream_t stream) {
    const float* pos     = (const float*)d_in[0];
    const int*   species = (const int*)  d_in[1];
    const float* glob    = (const float*)d_in[2];
    const float* embed   = (const float*)d_in[3];
    const float* glob_w  = (const float*)d_in[4];
    const float* rbf_w1  = (const float*)d_in[5];   // [2][8][64]
    const float* rbf_b1  = (const float*)d_in[6];   // [2][64]
    const float* rbf_w2  = (const float*)d_in[7];   // [2][64][192]
    const float* ws      = (const float*)d_in[8];   // [2][64][64]
    const float* wv      = (const float*)d_in[9];   // [2][64][64]
    const float* wout    = (const float*)d_in[10];  // [64]
    const float* scale   = (const float*)d_in[11];  // [1]

    float* wsf = (float*)d_ws;
    float* s0     = wsf;                        // 262144 floats
    float* s1     = wsf + 262144;               // 262144
    float* v1     = wsf + 524288;               // 1048576
    short* w2frag = (short*)(wsf + 1572864);    // 24576 shorts (12288 floats)
    float* wT4    = wsf + 1585152;              // 16384 floats
    _Float16* w1A = (_Float16*)(wsf + 1601536); // 2048 halfs (1024 floats)
    float* outp = (float*)d_out;

    setup_kernel<<<dim3(192 + BB * NN / 4), 256, 0, stream>>>(
        rbf_w2, ws, wv, rbf_w1, rbf_b1, species, glob, embed, glob_w,
        w2frag, wT4, w1A, s0);

    msg_kernel<0><<<dim3(NN * BB / 2), 256, 0, stream>>>(
        pos, s0, nullptr,
        (const half4*)w1A, w2frag, wT4, wout, scale,
        s1, v1, nullptr);

    msg_kernel<1><<<dim3(NN * BB / 2), 256, 0, stream>>>(
        pos, s1, v1,
        (const half4*)(w1A + 1024), w2frag + 12288, wT4 + 8192, wout, scale,
        nullptr, nullptr, outp);
}